// Round 1
// baseline (82.996 us; speedup 1.0000x reference)
//
#include <hip/hip_runtime.h>

// One-sided Chamfer: for each x_i (N=16384), min_j ||y_j - x_i||^2 over M=16384 y.
// t_ij = ||y_j||^2 - 2 x_i.y_j  (per-y precomputed as float4(-2y0,-2y1,-2y2,||y||^2))
// dist2_i = ||x_i||^2 + min_j t_ij
// Pure fp32-VALU problem: 3 FMA + 1 min per pair => ~13.7us floor at 78.6T lane-ops/s.

constexpr int TPB = 256;   // threads per block
constexpr int XPT = 4;     // x points per thread
constexpr int MAX_YCHUNK = 2048;  // LDS capacity: 2048 * 16B = 32KB

__global__ __launch_bounds__(TPB) void chamfer_main(
    const float* __restrict__ x, const float* __restrict__ y,
    float* __restrict__ part, int N, int M, int ychunk) {
  __shared__ float4 sy[MAX_YCHUNK];
  const int t = threadIdx.x;
  const int bx = blockIdx.x;       // x block (TPB*XPT x-points)
  const int s = blockIdx.y;        // y chunk index

  // Stage + transform this block's y chunk into LDS.
  for (int jj = t; jj < ychunk; jj += TPB) {
    const int j = s * ychunk + jj;
    if (j < M) {
      const float y0 = y[3 * j], y1 = y[3 * j + 1], y2 = y[3 * j + 2];
      sy[jj] = make_float4(-2.0f * y0, -2.0f * y1, -2.0f * y2,
                           y0 * y0 + y1 * y1 + y2 * y2);
    } else {
      sy[jj] = make_float4(0.0f, 0.0f, 0.0f, __builtin_inff());
    }
  }
  __syncthreads();

  float x0[XPT], x1[XPT], x2[XPT], mn[XPT];
#pragma unroll
  for (int k = 0; k < XPT; k++) {
    const int i = bx * (TPB * XPT) + k * TPB + t;
    const int ic = (i < N) ? i : 0;
    x0[k] = x[3 * ic];
    x1[k] = x[3 * ic + 1];
    x2[k] = x[3 * ic + 2];
    mn[k] = __builtin_inff();
  }

#pragma unroll 8
  for (int jj = 0; jj < ychunk; jj++) {
    const float4 q = sy[jj];  // wave-uniform address -> LDS broadcast, conflict-free
#pragma unroll
    for (int k = 0; k < XPT; k++) {
      const float tt = fmaf(x0[k], q.x, fmaf(x1[k], q.y, fmaf(x2[k], q.z, q.w)));
      mn[k] = fminf(mn[k], tt);
    }
  }

#pragma unroll
  for (int k = 0; k < XPT; k++) {
    const int i = bx * (TPB * XPT) + k * TPB + t;
    if (i < N) part[(size_t)s * N + i] = mn[k];
  }
}

__global__ __launch_bounds__(TPB) void chamfer_reduce(
    const float* __restrict__ x, const float* __restrict__ part,
    float* __restrict__ out, float* __restrict__ bsum, int N, int S) {
  const int t = threadIdx.x;
  const int i = blockIdx.x * TPB + t;

  float d = 0.0f;
  if (i < N) {
    float m = __builtin_inff();
#pragma unroll 8
    for (int s = 0; s < S; s++) m = fminf(m, part[(size_t)s * N + i]);
    const float a = x[3 * i], b = x[3 * i + 1], c = x[3 * i + 2];
    d = m + (a * a + b * b + c * c);
    out[1 + i] = d;
  }

  // Deterministic block sum: wave shuffle reduce, then cross-wave via LDS.
  float v = d;
#pragma unroll
  for (int off = 32; off > 0; off >>= 1) v += __shfl_down(v, off, 64);
  __shared__ float wsum[TPB / 64];
  if ((t & 63) == 0) wsum[t >> 6] = v;
  __syncthreads();
  if (t == 0) {
    float s = 0.0f;
#pragma unroll
    for (int w = 0; w < TPB / 64; w++) s += wsum[w];
    bsum[blockIdx.x] = s;
  }
}

__global__ __launch_bounds__(64) void chamfer_final(
    const float* __restrict__ bsum, float* __restrict__ out, int nb) {
  const int t = threadIdx.x;
  float v = 0.0f;
  for (int k = t; k < nb; k += 64) v += bsum[k];
#pragma unroll
  for (int off = 32; off > 0; off >>= 1) v += __shfl_down(v, off, 64);
  if (t == 0) out[0] = v;
}

extern "C" void kernel_launch(void* const* d_in, const int* in_sizes, int n_in,
                              void* d_out, int out_size, void* d_ws, size_t ws_size,
                              hipStream_t stream) {
  const float* x = (const float*)d_in[0];
  const float* y = (const float*)d_in[1];
  float* out = (float*)d_out;

  const int N = in_sizes[0] / 3;  // 16384
  const int M = in_sizes[1] / 3;  // 16384

  // Pick y-split count S so partials fit in workspace; keep ychunk <= MAX_YCHUNK.
  int S = 64;
  while (S > 8 && (size_t)S * N * sizeof(float) + 4096 > ws_size) S >>= 1;
  const int ychunk = (M + S - 1) / S;  // 256 at S=64

  float* part = (float*)d_ws;                       // [S][N]
  float* bsum = (float*)((char*)d_ws + (size_t)S * N * sizeof(float));

  const int xblocks = (N + TPB * XPT - 1) / (TPB * XPT);  // 16
  dim3 gridB(xblocks, S);
  chamfer_main<<<gridB, TPB, 0, stream>>>(x, y, part, N, M, ychunk);

  const int rblocks = (N + TPB - 1) / TPB;  // 64
  chamfer_reduce<<<rblocks, TPB, 0, stream>>>(x, part, out, bsum, N, S);

  chamfer_final<<<1, 64, 0, stream>>>(bsum, out, rblocks);
}